// Round 8
// baseline (856.471 us; speedup 1.0000x reference)
//
#include <hip/hip_runtime.h>
#include <hip/hip_bf16.h>

#define TT 200
#define NBATCH 256
#define HID 128
#define G4 512
#define VOC 50000

// R11 design notes:
// - R10 measured: total 856.3us, k2 614.6us (VALUBusy 41.7%, FETCH 82MB, VGPR 64,
//   0 conflicts). Readlane change confirmed (LDS broadcast -> VALU) but step only
//   8240->7375 cyc. Model: LDS ~3100, VALU ~3075 (parallel SIMDs) -> ~4000 cyc
//   of barrier/drain overhead across 3 __syncthreads/step.
// - R11 single change: in-loop __syncthreads() -> {s_waitcnt lgkmcnt(0); raw
//   s_barrier}. hipcc drains vmcnt(0) at every __syncthreads, forcing the
//   step-top prefetch globals (XW ~L2/L3, topo ~HBM, 300-900 cyc) to complete
//   by barrier A. All in-loop cross-thread hazards are LDS-only -> lgkmcnt(0)
//   suffices; prefetch stays in flight until its commit (compiler inserts the
//   per-wave vmcnt wait before the pf ds_write automatically).
// - Tripwires: absmax must stay 3.9e-3 (race check), FETCH ~82MB, VGPR 64.
// - Banked: c_lds[h][209] scalar reads conflict-free; don't vectorize (odd pad
//   is required for bank-freedom but breaks b64 alignment).

#define RL(v, l) __uint_as_float((unsigned)__builtin_amdgcn_readlane((int)__float_as_uint(v), (l)))

// lgkm-only barrier: LDS visibility without the vmcnt(0) drain of __syncthreads.
#define BAR_LGKM() do { \
    asm volatile("s_waitcnt lgkmcnt(0)" ::: "memory"); \
    __builtin_amdgcn_s_barrier(); \
} while (0)

// ---------------- Kernel XW: XW = ET @ W + b  (50000 x 512) ----------------
// 512 thr: 32 rows x 512 cols per block. jq=tid&127 -> cols 4jq..4jq+3,
// rg=tid>>7 -> rows 8rg..8rg+8. ET tile (16KB) staged once, then pure compute.
__global__ __launch_bounds__(512) void kxw(
    const float* __restrict__ ET,       // (V, H)
    const float* __restrict__ W,        // (H, 4H)
    const float* __restrict__ b,        // (4H)
    float* __restrict__ XW)             // (V, 4H)
{
    const int tid = threadIdx.x;
    const int jq = tid & 127;
    const int j0 = jq * 4;
    const int rg = tid >> 7;            // 0..3, wave-uniform
    const int rb = blockIdx.x * 32;

    __shared__ __align__(16) float et[32][HID];   // 16 KB

    // stage ET tile: 4096 floats, thread loads 8 consecutive (2x float4)
    {
        const int bse = tid * 8;
        const int r = bse >> 7, c = bse & 127;
        int row = rb + r; row = row < VOC ? row : VOC - 1;
        const float4* src = (const float4*)(ET + (size_t)row * HID + c);
        float4 v0 = src[0], v1 = src[1];
        *((float4*)&et[r][c])     = v0;
        *((float4*)&et[r][c + 4]) = v1;
    }
    __syncthreads();

    float acc[8][4];
    #pragma unroll
    for (int r = 0; r < 8; ++r) {
        acc[r][0] = 0.f; acc[r][1] = 0.f; acc[r][2] = 0.f; acc[r][3] = 0.f;
    }

    const float4* W4 = (const float4*)W;     // W[k][j0..j0+3] = W4[k*128 + jq]
    #pragma unroll 2
    for (int k4 = 0; k4 < 32; ++k4) {
        const float4 w0 = W4[(size_t)(4 * k4 + 0) * 128 + jq];
        const float4 w1 = W4[(size_t)(4 * k4 + 1) * 128 + jq];
        const float4 w2 = W4[(size_t)(4 * k4 + 2) * 128 + jq];
        const float4 w3 = W4[(size_t)(4 * k4 + 3) * 128 + jq];
        #pragma unroll
        for (int r = 0; r < 8; ++r) {
            const float4 e4 = *(const float4*)&et[rg * 8 + r][4 * k4];  // broadcast
            acc[r][0] = fmaf(e4.x, w0.x, acc[r][0]);
            acc[r][0] = fmaf(e4.y, w1.x, acc[r][0]);
            acc[r][0] = fmaf(e4.z, w2.x, acc[r][0]);
            acc[r][0] = fmaf(e4.w, w3.x, acc[r][0]);
            acc[r][1] = fmaf(e4.x, w0.y, acc[r][1]);
            acc[r][1] = fmaf(e4.y, w1.y, acc[r][1]);
            acc[r][1] = fmaf(e4.z, w2.y, acc[r][1]);
            acc[r][1] = fmaf(e4.w, w3.y, acc[r][1]);
            acc[r][2] = fmaf(e4.x, w0.z, acc[r][2]);
            acc[r][2] = fmaf(e4.y, w1.z, acc[r][2]);
            acc[r][2] = fmaf(e4.z, w2.z, acc[r][2]);
            acc[r][2] = fmaf(e4.w, w3.z, acc[r][2]);
            acc[r][3] = fmaf(e4.x, w0.w, acc[r][3]);
            acc[r][3] = fmaf(e4.y, w1.w, acc[r][3]);
            acc[r][3] = fmaf(e4.z, w2.w, acc[r][3]);
            acc[r][3] = fmaf(e4.w, w3.w, acc[r][3]);
        }
    }

    const float4 bj = *(const float4*)&b[j0];
    #pragma unroll
    for (int r = 0; r < 8; ++r) {
        const int row = rb + rg * 8 + r;
        if (row < VOC) {
            float4 o;
            o.x = acc[r][0] + bj.x; o.y = acc[r][1] + bj.y;
            o.z = acc[r][2] + bj.z; o.w = acc[r][3] + bj.w;
            *(float4*)&XW[(size_t)row * G4 + j0] = o;
        }
    }
}

// ---------------- Kernel 2: recurrence, one 1024-thr block per n ----------------
// R10 structure; in-loop barriers are lgkm-only (prefetch globals stay in flight
// across bars A and B). h history in regs (hreg[25], group g=tid>>7 owns rows
// [25g,25g+25)), c history in LDS (c_lds[h][209], conflict-free), U in regs
// (ucol[64], K-half kh=tid>>9). 3 barriers/step.
__global__ __launch_bounds__(1024) void k2_recur(
    const float* __restrict__ topo,     // (T, N, T)
    const float* __restrict__ mask,     // (T, N)
    const float* __restrict__ U,        // (H, 4H)
    const int*   __restrict__ seq,      // (T, N)
    const float* __restrict__ XW,       // (V, 4H)
    float* __restrict__ hmT)            // (H, N) transposed h_mean
{
    const int n    = blockIdx.x;
    const int tid  = threadIdx.x;
    const int g    = __builtin_amdgcn_readfirstlane(tid >> 7);   // 0..7
    const int h    = tid & 127;
    const int kh   = __builtin_amdgcn_readfirstlane(tid >> 9);   // 0..1
    const int j    = tid & 511;
    const int lane = tid & 63;

    __shared__ float c_lds[HID][209];                 // 104.5 KB, c_lds[h][t']
    __shared__ __align__(16) float topoS[2][8][32];   // double-buffered topo row
    __shared__ float part_h[8][HID];
    __shared__ float part_c[8][HID];
    __shared__ __align__(16) float hsum[HID];
    __shared__ float csum[HID];
    __shared__ float pB[2][G4];
    __shared__ float xgl[2][G4];
    __shared__ int   seq_l[TT];
    __shared__ float mask_l[TT];

    float ucol[64];
    #pragma unroll
    for (int kk = 0; kk < 64; ++kk) ucol[kk] = U[(size_t)(kh * 64 + kk) * G4 + j];

    float hreg[25];
    #pragma unroll
    for (int k = 0; k < 25; ++k) hreg[k] = 0.f;
    for (int i = tid; i < HID * 209; i += 1024) (&c_lds[0][0])[i] = 0.f;

    // one-time preload: per-n sequence + mask rows (kills per-step s_load chain)
    if (tid < TT) {
        seq_l[tid]  = seq[tid * NBATCH + n];
        mask_l[tid] = mask[tid * NBATCH + n];
    }
    // prologue stage for t=0 (addresses straight from global, uniform)
    if (tid < G4) {
        xgl[0][tid] = XW[(size_t)seq[n] * G4 + tid];
    } else if (tid < 768) {
        const int tt = tid - 512;
        const int gg = tt >> 5, ii = tt & 31;
        topoS[0][gg][ii] = (ii < 25)
            ? topo[(size_t)n * TT + 25 * gg + ii] : 0.f;   // t=0 row
    }

    float hmacc = 0.f, len = 0.f;
    __syncthreads();   // once, before loop: full drain is fine

    for (int t = 0; t < TT; ++t) {
        const int cur = t & 1, nxt = cur ^ 1;

        // ---- issue prefetch for step t+1 (registers; committed before bar C;
        //      stays in flight across bars A and B thanks to lgkm-only barriers) ----
        const int tn = (t + 1 < TT) ? t + 1 : t;
        float pf = 0.f;
        if (tid < G4) {
            pf = XW[(size_t)seq_l[tn] * G4 + tid];
        } else if (tid < 768) {
            const int tt = tid - 512;
            const int gg = tt >> 5, ii = tt & 31;
            pf = (ii < 25)
                ? topo[((size_t)tn * NBATCH + n) * TT + 25 * gg + ii] : 0.f;
        }
        const float m = mask_l[t];

        // ---- phase A: topo row via lane-distribute + readlane; h from regs,
        //      c from LDS (25x ds_read_b32, conflict-free) ----
        const float tval = topoS[cur][g][lane & 31];   // lane k<25 holds topo[k]
        float ah0 = 0.f, ah1 = 0.f, ac0 = 0.f, ac1 = 0.f;
        const int base = 25 * g;
        const float* crow = &c_lds[h][0];
        #pragma unroll
        for (int kk = 0; kk < 6; ++kk) {
            if (base + 4 * kk < t) {        // perf guard only; data is 0 beyond t
                const float t0 = RL(tval, 4 * kk + 0);
                const float t1 = RL(tval, 4 * kk + 1);
                const float t2 = RL(tval, 4 * kk + 2);
                const float t3 = RL(tval, 4 * kk + 3);
                ah0 = fmaf(t0, hreg[4*kk+0], ah0);
                ac0 = fmaf(t0, crow[base+4*kk+0], ac0);
                ah1 = fmaf(t1, hreg[4*kk+1], ah1);
                ac1 = fmaf(t1, crow[base+4*kk+1], ac1);
                ah0 = fmaf(t2, hreg[4*kk+2], ah0);
                ac0 = fmaf(t2, crow[base+4*kk+2], ac0);
                ah1 = fmaf(t3, hreg[4*kk+3], ah1);
                ac1 = fmaf(t3, crow[base+4*kk+3], ac1);
            }
        }
        if (base + 24 < t) {
            const float tpl = RL(tval, 24);
            ah0 = fmaf(tpl, hreg[24], ah0);
            ac0 = fmaf(tpl, crow[base+24], ac0);
        }
        part_h[g][h] = ah0 + ah1;
        part_c[g][h] = ac0 + ac1;
        BAR_LGKM();                                             // (A)

        if (tid < HID) {
            float s = 0.f;
            #pragma unroll
            for (int gg = 0; gg < 8; ++gg) s += part_h[gg][tid];
            hsum[tid] = s;
        } else if (tid < 2 * HID) {
            const int hh = tid - HID;
            float s = 0.f;
            #pragma unroll
            for (int gg = 0; gg < 8; ++gg) s += part_c[gg][hh];
            csum[hh] = s;
        }
        BAR_LGKM();                                             // (B)

        // ---- phase B: pB[kh][j] = hsum[kh-half] . U-half column, hsum via
        //      lane-distribute + readlane ----
        {
            const float hval = hsum[kh * 64 + lane];   // lane k holds hsum[kh*64+k]
            float a0 = 0.f, a1 = 0.f, a2 = 0.f, a3 = 0.f;
            #pragma unroll
            for (int q = 0; q < 16; ++q) {
                a0 = fmaf(RL(hval, 4*q+0), ucol[4*q+0], a0);
                a1 = fmaf(RL(hval, 4*q+1), ucol[4*q+1], a1);
                a2 = fmaf(RL(hval, 4*q+2), ucol[4*q+2], a2);
                a3 = fmaf(RL(hval, 4*q+3), ucol[4*q+3], a3);
            }
            pB[kh][j] = (a0 + a1) + (a2 + a3);
        }
        // commit prefetch to the nxt buffers (compiler inserts the vmcnt wait
        // for pf right here; separated from next phase A by bar C)
        if (tid < G4) {
            xgl[nxt][tid] = pf;
        } else if (tid < 768) {
            const int tt = tid - 512;
            topoS[nxt][tt >> 5][tt & 31] = pf;
        }
        BAR_LGKM();                                             // (C)

        // ---- cell: owning group g* = t/25 (wave-uniform branch) ----
        const int gstar = t / 25;
        if (g == gstar) {
            const float iv = pB[0][h]       + pB[1][h]       + xgl[cur][h];
            const float fv = pB[0][128+h]   + pB[1][128+h]   + xgl[cur][128+h];
            const float ov = pB[0][256+h]   + pB[1][256+h]   + xgl[cur][256+h];
            const float gv = pB[0][384+h]   + pB[1][384+h]   + xgl[cur][384+h];
            const float si = 1.f / (1.f + expf(-iv));
            const float sf = 1.f / (1.f + expf(-fv));
            const float so = 1.f / (1.f + expf(-ov));
            const float tg = tanhf(gv);
            const float cn = m * (sf * csum[h] + si * tg);
            const float hn = m * (so * tanhf(cn));
            const int kt = t - 25 * gstar;
            #pragma unroll
            for (int k = 0; k < 25; ++k) if (k == kt) hreg[k] = hn;
            c_lds[h][t] = cn;
            hmacc = fmaf(m, hn, hmacc);
        }
        len += m;
        // next phase A reads topoS[nxt] (written before bar C) and c_lds (same-
        // thread). part_/hsum/csum/pB rewrites are >=1 barrier from their readers.
    }

    part_h[g][h] = hmacc;     // unique slot per thread
    __syncthreads();
    if (tid < HID) {
        float s = 0.f;
        #pragma unroll
        for (int gg = 0; gg < 8; ++gg) s += part_h[gg][tid];
        hmT[(size_t)tid * NBATCH + n] = s / len;   // transposed for k3
    }
}

// ---------------- Kernel 3: out = h_mean @ W_out + b_out  (k-outer matvec) ----------------
// 512 thr: v = column; acc[32] rows; Wout coalesced, hmT row-slice via s_load.
__global__ __launch_bounds__(512) void k3_out(
    const float* __restrict__ hmT,     // (H, N)
    const float* __restrict__ Wout,    // (H, V)
    const float* __restrict__ bout,    // (V)
    float* __restrict__ out)           // (N, V)
{
    const int tid = threadIdx.x;
    const int v = blockIdx.x * 512 + tid;
    const int r0 = blockIdx.y * 32;
    const int vc = v < VOC ? v : VOC - 1;

    float acc[32];
    #pragma unroll
    for (int r = 0; r < 32; ++r) acc[r] = 0.f;

    #pragma unroll 2
    for (int k = 0; k < HID; ++k) {
        const float wv = Wout[(size_t)k * VOC + vc];   // coalesced vector load
        const float* hr = hmT + k * NBATCH + r0;       // uniform -> s_load
        #pragma unroll
        for (int r = 0; r < 32; ++r) acc[r] = fmaf(hr[r], wv, acc[r]);
    }
    const float bv = bout[vc];
    if (v < VOC) {
        for (int r = 0; r < 32; ++r)
            out[(size_t)(r0 + r) * VOC + v] = acc[r] + bv;
    }
}

extern "C" void kernel_launch(void* const* d_in, const int* in_sizes, int n_in,
                              void* d_out, int out_size, void* d_ws, size_t ws_size,
                              hipStream_t stream) {
    const int*   seq  = (const int*)d_in[0];     // (T,N) int32
    const float* msk  = (const float*)d_in[1];   // (T,N)
    const float* topo = (const float*)d_in[2];   // (T,N,T)
    const float* W    = (const float*)d_in[3];   // (H,4H)
    const float* U    = (const float*)d_in[4];   // (H,4H)
    const float* b    = (const float*)d_in[5];   // (4H)
    const float* ET   = (const float*)d_in[6];   // (V,H)
    const float* Wout = (const float*)d_in[7];   // (H,V)
    const float* bout = (const float*)d_in[8];   // (V)
    float* out = (float*)d_out;

    float* XW  = (float*)d_ws;                                   // 102.4 MB
    float* hmT = (float*)((char*)d_ws + (size_t)VOC * G4 * sizeof(float)); // +128 KB

    kxw<<<(VOC + 31) / 32, 512, 0, stream>>>(ET, W, b, XW);
    k2_recur<<<NBATCH, 1024, 0, stream>>>(topo, msk, U, seq, XW, hmT);
    k3_out<<<dim3(98, 8), 512, 0, stream>>>(hmT, Wout, bout, out);
}

// Round 9
// 747.625 us; speedup vs baseline: 1.1456x; 1.1456x over previous
//
#include <hip/hip_runtime.h>
#include <hip/hip_bf16.h>

#define TT 200
#define NBATCH 256
#define HID 128
#define G4 512
#define VOC 50000

// R12 design notes:
// - R11 measured NEUTRAL (618 vs 615): lgkm-only barriers bought nothing ->
//   prefetch latency was already hidden by phase A before bar A. Banked: barrier
//   DRAIN is not a cost; phase/barrier SERIALIZATION is the remaining suspect.
// - Model: step 7420 cyc = A ~2600 + B ~1100 + commit/cell ~500 + RESIDUAL
//   ~3200 across {reduce phase: 4 waves work / 12 idle} + 3 barrier round-trips.
// - R12 single change: fold the reduce into phase B. Each phase-B thread sums
//   part_h[0..8][kh*64+lane] itself (8x ds_read_b32, 2-way conflict = free);
//   cell's csum becomes a register csr = sum part_c[gg][h] computed by g* threads
//   in the phase-B region. Deletes barrier B, the reduce phase, hsum/csum.
//   3 barriers/step -> 2. Phase A and cell math byte-identical.
// - Tripwires: FETCH ~82MB (balloon => allocator demotion => revert), VGPR<=70,
//   absmax 3.9e-3.
// - Banked: c_lds[h][209] conflict-free scalar reads - don't vectorize.

#define RL(v, l) __uint_as_float((unsigned)__builtin_amdgcn_readlane((int)__float_as_uint(v), (l)))

// lgkm-only barrier: LDS visibility without the vmcnt(0) drain of __syncthreads.
#define BAR_LGKM() do { \
    asm volatile("s_waitcnt lgkmcnt(0)" ::: "memory"); \
    __builtin_amdgcn_s_barrier(); \
} while (0)

// ---------------- Kernel XW: XW = ET @ W + b  (50000 x 512) ----------------
// 512 thr: 32 rows x 512 cols per block. jq=tid&127 -> cols 4jq..4jq+3,
// rg=tid>>7 -> rows 8rg..8rg+8. ET tile (16KB) staged once, then pure compute.
__global__ __launch_bounds__(512) void kxw(
    const float* __restrict__ ET,       // (V, H)
    const float* __restrict__ W,        // (H, 4H)
    const float* __restrict__ b,        // (4H)
    float* __restrict__ XW)             // (V, 4H)
{
    const int tid = threadIdx.x;
    const int jq = tid & 127;
    const int j0 = jq * 4;
    const int rg = tid >> 7;            // 0..3, wave-uniform
    const int rb = blockIdx.x * 32;

    __shared__ __align__(16) float et[32][HID];   // 16 KB

    // stage ET tile: 4096 floats, thread loads 8 consecutive (2x float4)
    {
        const int bse = tid * 8;
        const int r = bse >> 7, c = bse & 127;
        int row = rb + r; row = row < VOC ? row : VOC - 1;
        const float4* src = (const float4*)(ET + (size_t)row * HID + c);
        float4 v0 = src[0], v1 = src[1];
        *((float4*)&et[r][c])     = v0;
        *((float4*)&et[r][c + 4]) = v1;
    }
    __syncthreads();

    float acc[8][4];
    #pragma unroll
    for (int r = 0; r < 8; ++r) {
        acc[r][0] = 0.f; acc[r][1] = 0.f; acc[r][2] = 0.f; acc[r][3] = 0.f;
    }

    const float4* W4 = (const float4*)W;     // W[k][j0..j0+3] = W4[k*128 + jq]
    #pragma unroll 2
    for (int k4 = 0; k4 < 32; ++k4) {
        const float4 w0 = W4[(size_t)(4 * k4 + 0) * 128 + jq];
        const float4 w1 = W4[(size_t)(4 * k4 + 1) * 128 + jq];
        const float4 w2 = W4[(size_t)(4 * k4 + 2) * 128 + jq];
        const float4 w3 = W4[(size_t)(4 * k4 + 3) * 128 + jq];
        #pragma unroll
        for (int r = 0; r < 8; ++r) {
            const float4 e4 = *(const float4*)&et[rg * 8 + r][4 * k4];  // broadcast
            acc[r][0] = fmaf(e4.x, w0.x, acc[r][0]);
            acc[r][0] = fmaf(e4.y, w1.x, acc[r][0]);
            acc[r][0] = fmaf(e4.z, w2.x, acc[r][0]);
            acc[r][0] = fmaf(e4.w, w3.x, acc[r][0]);
            acc[r][1] = fmaf(e4.x, w0.y, acc[r][1]);
            acc[r][1] = fmaf(e4.y, w1.y, acc[r][1]);
            acc[r][1] = fmaf(e4.z, w2.y, acc[r][1]);
            acc[r][1] = fmaf(e4.w, w3.y, acc[r][1]);
            acc[r][2] = fmaf(e4.x, w0.z, acc[r][2]);
            acc[r][2] = fmaf(e4.y, w1.z, acc[r][2]);
            acc[r][2] = fmaf(e4.z, w2.z, acc[r][2]);
            acc[r][2] = fmaf(e4.w, w3.z, acc[r][2]);
            acc[r][3] = fmaf(e4.x, w0.w, acc[r][3]);
            acc[r][3] = fmaf(e4.y, w1.w, acc[r][3]);
            acc[r][3] = fmaf(e4.z, w2.w, acc[r][3]);
            acc[r][3] = fmaf(e4.w, w3.w, acc[r][3]);
        }
    }

    const float4 bj = *(const float4*)&b[j0];
    #pragma unroll
    for (int r = 0; r < 8; ++r) {
        const int row = rb + rg * 8 + r;
        if (row < VOC) {
            float4 o;
            o.x = acc[r][0] + bj.x; o.y = acc[r][1] + bj.y;
            o.z = acc[r][2] + bj.z; o.w = acc[r][3] + bj.w;
            *(float4*)&XW[(size_t)row * G4 + j0] = o;
        }
    }
}

// ---------------- Kernel 2: recurrence, one 1024-thr block per n ----------------
// R11 structure with the reduce phase folded into phase B (2 barriers/step).
// h history in regs (hreg[25], group g=tid>>7 owns rows [25g,25g+25)),
// c history in LDS (c_lds[h][209], conflict-free), U in regs (ucol[64]).
// Phase B: hval = sum_gg part_h[gg][kh*64+lane] (8x b32, 2-way = free), then
// readlane-FMA as before. Cell csum -> register csr (computed by g* threads
// between bars A and C, where part_c is stable).
__global__ __launch_bounds__(1024) void k2_recur(
    const float* __restrict__ topo,     // (T, N, T)
    const float* __restrict__ mask,     // (T, N)
    const float* __restrict__ U,        // (H, 4H)
    const int*   __restrict__ seq,      // (T, N)
    const float* __restrict__ XW,       // (V, 4H)
    float* __restrict__ hmT)            // (H, N) transposed h_mean
{
    const int n    = blockIdx.x;
    const int tid  = threadIdx.x;
    const int g    = __builtin_amdgcn_readfirstlane(tid >> 7);   // 0..7
    const int h    = tid & 127;
    const int kh   = __builtin_amdgcn_readfirstlane(tid >> 9);   // 0..1
    const int j    = tid & 511;
    const int lane = tid & 63;

    __shared__ float c_lds[HID][209];                 // 104.5 KB, c_lds[h][t']
    __shared__ __align__(16) float topoS[2][8][32];   // double-buffered topo row
    __shared__ float part_h[8][HID];
    __shared__ float part_c[8][HID];
    __shared__ float pB[2][G4];
    __shared__ float xgl[2][G4];
    __shared__ int   seq_l[TT];
    __shared__ float mask_l[TT];

    float ucol[64];
    #pragma unroll
    for (int kk = 0; kk < 64; ++kk) ucol[kk] = U[(size_t)(kh * 64 + kk) * G4 + j];

    float hreg[25];
    #pragma unroll
    for (int k = 0; k < 25; ++k) hreg[k] = 0.f;
    for (int i = tid; i < HID * 209; i += 1024) (&c_lds[0][0])[i] = 0.f;

    // one-time preload: per-n sequence + mask rows (kills per-step s_load chain)
    if (tid < TT) {
        seq_l[tid]  = seq[tid * NBATCH + n];
        mask_l[tid] = mask[tid * NBATCH + n];
    }
    // prologue stage for t=0 (addresses straight from global, uniform)
    if (tid < G4) {
        xgl[0][tid] = XW[(size_t)seq[n] * G4 + tid];
    } else if (tid < 768) {
        const int tt = tid - 512;
        const int gg = tt >> 5, ii = tt & 31;
        topoS[0][gg][ii] = (ii < 25)
            ? topo[(size_t)n * TT + 25 * gg + ii] : 0.f;   // t=0 row
    }

    float hmacc = 0.f, len = 0.f;
    __syncthreads();   // once, before loop: full drain is fine

    for (int t = 0; t < TT; ++t) {
        const int cur = t & 1, nxt = cur ^ 1;
        const int gstar = t / 25;

        // ---- issue prefetch for step t+1 (registers; committed before bar C) ----
        const int tn = (t + 1 < TT) ? t + 1 : t;
        float pf = 0.f;
        if (tid < G4) {
            pf = XW[(size_t)seq_l[tn] * G4 + tid];
        } else if (tid < 768) {
            const int tt = tid - 512;
            const int gg = tt >> 5, ii = tt & 31;
            pf = (ii < 25)
                ? topo[((size_t)tn * NBATCH + n) * TT + 25 * gg + ii] : 0.f;
        }
        const float m = mask_l[t];

        // ---- phase A: topo row via lane-distribute + readlane; h from regs,
        //      c from LDS (25x ds_read_b32, conflict-free) ----
        const float tval = topoS[cur][g][lane & 31];   // lane k<25 holds topo[k]
        float ah0 = 0.f, ah1 = 0.f, ac0 = 0.f, ac1 = 0.f;
        const int base = 25 * g;
        const float* crow = &c_lds[h][0];
        #pragma unroll
        for (int kk = 0; kk < 6; ++kk) {
            if (base + 4 * kk < t) {        // perf guard only; data is 0 beyond t
                const float t0 = RL(tval, 4 * kk + 0);
                const float t1 = RL(tval, 4 * kk + 1);
                const float t2 = RL(tval, 4 * kk + 2);
                const float t3 = RL(tval, 4 * kk + 3);
                ah0 = fmaf(t0, hreg[4*kk+0], ah0);
                ac0 = fmaf(t0, crow[base+4*kk+0], ac0);
                ah1 = fmaf(t1, hreg[4*kk+1], ah1);
                ac1 = fmaf(t1, crow[base+4*kk+1], ac1);
                ah0 = fmaf(t2, hreg[4*kk+2], ah0);
                ac0 = fmaf(t2, crow[base+4*kk+2], ac0);
                ah1 = fmaf(t3, hreg[4*kk+3], ah1);
                ac1 = fmaf(t3, crow[base+4*kk+3], ac1);
            }
        }
        if (base + 24 < t) {
            const float tpl = RL(tval, 24);
            ah0 = fmaf(tpl, hreg[24], ah0);
            ac0 = fmaf(tpl, crow[base+24], ac0);
        }
        part_h[g][h] = ah0 + ah1;
        part_c[g][h] = ac0 + ac1;
        BAR_LGKM();                                             // (A)

        // ---- phase B (reduce folded in): hval = sum_gg part_h[gg][col],
        //      then pB[kh][j] = hsum-half . U-half column via readlane ----
        {
            const int col = kh * 64 + lane;
            const float s0 = part_h[0][col] + part_h[1][col];
            const float s1 = part_h[2][col] + part_h[3][col];
            const float s2 = part_h[4][col] + part_h[5][col];
            const float s3 = part_h[6][col] + part_h[7][col];
            const float hval = (s0 + s1) + (s2 + s3);  // lane k holds hsum[kh*64+k]
            float a0 = 0.f, a1 = 0.f, a2 = 0.f, a3 = 0.f;
            #pragma unroll
            for (int q = 0; q < 16; ++q) {
                a0 = fmaf(RL(hval, 4*q+0), ucol[4*q+0], a0);
                a1 = fmaf(RL(hval, 4*q+1), ucol[4*q+1], a1);
                a2 = fmaf(RL(hval, 4*q+2), ucol[4*q+2], a2);
                a3 = fmaf(RL(hval, 4*q+3), ucol[4*q+3], a3);
            }
            pB[kh][j] = (a0 + a1) + (a2 + a3);
        }
        // cell's csum as a register (part_c stable between bars A and C)
        float csr = 0.f;
        if (g == gstar) {
            const float c0 = part_c[0][h] + part_c[1][h];
            const float c1 = part_c[2][h] + part_c[3][h];
            const float c2 = part_c[4][h] + part_c[5][h];
            const float c3 = part_c[6][h] + part_c[7][h];
            csr = (c0 + c1) + (c2 + c3);
        }
        // commit prefetch to the nxt buffers (vmcnt wait lands here)
        if (tid < G4) {
            xgl[nxt][tid] = pf;
        } else if (tid < 768) {
            const int tt = tid - 512;
            topoS[nxt][tt >> 5][tt & 31] = pf;
        }
        BAR_LGKM();                                             // (C)

        // ---- cell: owning group g* = t/25 (wave-uniform branch) ----
        if (g == gstar) {
            const float iv = pB[0][h]       + pB[1][h]       + xgl[cur][h];
            const float fv = pB[0][128+h]   + pB[1][128+h]   + xgl[cur][128+h];
            const float ov = pB[0][256+h]   + pB[1][256+h]   + xgl[cur][256+h];
            const float gv = pB[0][384+h]   + pB[1][384+h]   + xgl[cur][384+h];
            const float si = 1.f / (1.f + expf(-iv));
            const float sf = 1.f / (1.f + expf(-fv));
            const float so = 1.f / (1.f + expf(-ov));
            const float tg = tanhf(gv);
            const float cn = m * (sf * csr + si * tg);
            const float hn = m * (so * tanhf(cn));
            const int kt = t - 25 * gstar;
            #pragma unroll
            for (int k = 0; k < 25; ++k) if (k == kt) hreg[k] = hn;
            c_lds[h][t] = cn;
            hmacc = fmaf(m, hn, hmacc);
        }
        len += m;
        // hazards: part_h/part_c written before bar A, read between bars A and C,
        // rewritten next step only after bar C (next phase A). pB written before
        // bar C, read after bar C, rewritten after next bar A. xgl[cur] read in
        // cell(t); rewritten at commit(t+1) which is after bar A(t+1) -- cell(t)
        // completes before the g* waves arrive at bar A(t+1), so safe.
    }

    part_h[g][h] = hmacc;     // unique slot per thread (all pB reads done pre-barC)
    __syncthreads();
    if (tid < HID) {
        float s = 0.f;
        #pragma unroll
        for (int gg = 0; gg < 8; ++gg) s += part_h[gg][tid];
        hmT[(size_t)tid * NBATCH + n] = s / len;   // transposed for k3
    }
}

// ---------------- Kernel 3: out = h_mean @ W_out + b_out  (k-outer matvec) ----------------
// 512 thr: v = column; acc[32] rows; Wout coalesced, hmT row-slice via s_load.
__global__ __launch_bounds__(512) void k3_out(
    const float* __restrict__ hmT,     // (H, N)
    const float* __restrict__ Wout,    // (H, V)
    const float* __restrict__ bout,    // (V)
    float* __restrict__ out)           // (N, V)
{
    const int tid = threadIdx.x;
    const int v = blockIdx.x * 512 + tid;
    const int r0 = blockIdx.y * 32;
    const int vc = v < VOC ? v : VOC - 1;

    float acc[32];
    #pragma unroll
    for (int r = 0; r < 32; ++r) acc[r] = 0.f;

    #pragma unroll 2
    for (int k = 0; k < HID; ++k) {
        const float wv = Wout[(size_t)k * VOC + vc];   // coalesced vector load
        const float* hr = hmT + k * NBATCH + r0;       // uniform -> s_load
        #pragma unroll
        for (int r = 0; r < 32; ++r) acc[r] = fmaf(hr[r], wv, acc[r]);
    }
    const float bv = bout[vc];
    if (v < VOC) {
        for (int r = 0; r < 32; ++r)
            out[(size_t)(r0 + r) * VOC + v] = acc[r] + bv;
    }
}

extern "C" void kernel_launch(void* const* d_in, const int* in_sizes, int n_in,
                              void* d_out, int out_size, void* d_ws, size_t ws_size,
                              hipStream_t stream) {
    const int*   seq  = (const int*)d_in[0];     // (T,N) int32
    const float* msk  = (const float*)d_in[1];   // (T,N)
    const float* topo = (const float*)d_in[2];   // (T,N,T)
    const float* W    = (const float*)d_in[3];   // (H,4H)
    const float* U    = (const float*)d_in[4];   // (H,4H)
    const float* b    = (const float*)d_in[5];   // (4H)
    const float* ET   = (const float*)d_in[6];   // (V,H)
    const float* Wout = (const float*)d_in[7];   // (H,V)
    const float* bout = (const float*)d_in[8];   // (V)
    float* out = (float*)d_out;

    float* XW  = (float*)d_ws;                                   // 102.4 MB
    float* hmT = (float*)((char*)d_ws + (size_t)VOC * G4 * sizeof(float)); // +128 KB

    kxw<<<(VOC + 31) / 32, 512, 0, stream>>>(ET, W, b, XW);
    k2_recur<<<NBATCH, 1024, 0, stream>>>(topo, msk, U, seq, XW, hmT);
    k3_out<<<dim3(98, 8), 512, 0, stream>>>(hmT, Wout, bout, out);
}

// Round 10
// 726.800 us; speedup vs baseline: 1.1784x; 1.0287x over previous
//
#include <hip/hip_runtime.h>
#include <hip/hip_bf16.h>

#define TT 200
#define NBATCH 256
#define HID 128
#define G4 512
#define VOC 50000

// R13 design notes:
// - R12 measured: k2 615->503us (reduce-fold + 2 barriers worked; VALUBusy 54%,
//   FETCH 82MB, VGPR 64). Step 6030 cyc vs ~4000 floor: ~2000 cyc = phase-A wave
//   imbalance (group g idle until t>25g; max-group cost gates every barrier).
// - R13 k2 change: mod-8 interleaved t' ownership. Group g owns t' in
//   {g, g+8, ...} (hreg[i] = h(g+8i)) -> every group has ~t/8 active terms at
//   EVERY t. Index remap only: staging topoS[g][i]=row[g+8i], guards g+32kk<t,
//   crow[g+32kk+8q], gstar=t&7, kt=t>>3. Instr/reg/LDS/barriers unchanged.
// - R13 k3 change (separate kernel, clean attribution): float4 Wout loads
//   (was 128 scalar b32/thread), 4 cols x 16 rows per thread, s_loads halved.
// - Tripwires: FETCH ~82MB, VGPR 64/112 (k2), absmax 3.9e-3.
// - Banked: c_lds[h][209] conflict-free scalar reads - don't vectorize.
//   Barrier DRAIN is not a cost (R11); readlane >> LDS broadcast (R10).

#define RL(v, l) __uint_as_float((unsigned)__builtin_amdgcn_readlane((int)__float_as_uint(v), (l)))

// lgkm-only barrier: LDS visibility without the vmcnt(0) drain of __syncthreads.
#define BAR_LGKM() do { \
    asm volatile("s_waitcnt lgkmcnt(0)" ::: "memory"); \
    __builtin_amdgcn_s_barrier(); \
} while (0)

// ---------------- Kernel XW: XW = ET @ W + b  (50000 x 512) ----------------
// 512 thr: 32 rows x 512 cols per block. jq=tid&127 -> cols 4jq..4jq+3,
// rg=tid>>7 -> rows 8rg..8rg+8. ET tile (16KB) staged once, then pure compute.
__global__ __launch_bounds__(512) void kxw(
    const float* __restrict__ ET,       // (V, H)
    const float* __restrict__ W,        // (H, 4H)
    const float* __restrict__ b,        // (4H)
    float* __restrict__ XW)             // (V, 4H)
{
    const int tid = threadIdx.x;
    const int jq = tid & 127;
    const int j0 = jq * 4;
    const int rg = tid >> 7;            // 0..3, wave-uniform
    const int rb = blockIdx.x * 32;

    __shared__ __align__(16) float et[32][HID];   // 16 KB

    // stage ET tile: 4096 floats, thread loads 8 consecutive (2x float4)
    {
        const int bse = tid * 8;
        const int r = bse >> 7, c = bse & 127;
        int row = rb + r; row = row < VOC ? row : VOC - 1;
        const float4* src = (const float4*)(ET + (size_t)row * HID + c);
        float4 v0 = src[0], v1 = src[1];
        *((float4*)&et[r][c])     = v0;
        *((float4*)&et[r][c + 4]) = v1;
    }
    __syncthreads();

    float acc[8][4];
    #pragma unroll
    for (int r = 0; r < 8; ++r) {
        acc[r][0] = 0.f; acc[r][1] = 0.f; acc[r][2] = 0.f; acc[r][3] = 0.f;
    }

    const float4* W4 = (const float4*)W;     // W[k][j0..j0+3] = W4[k*128 + jq]
    #pragma unroll 2
    for (int k4 = 0; k4 < 32; ++k4) {
        const float4 w0 = W4[(size_t)(4 * k4 + 0) * 128 + jq];
        const float4 w1 = W4[(size_t)(4 * k4 + 1) * 128 + jq];
        const float4 w2 = W4[(size_t)(4 * k4 + 2) * 128 + jq];
        const float4 w3 = W4[(size_t)(4 * k4 + 3) * 128 + jq];
        #pragma unroll
        for (int r = 0; r < 8; ++r) {
            const float4 e4 = *(const float4*)&et[rg * 8 + r][4 * k4];  // broadcast
            acc[r][0] = fmaf(e4.x, w0.x, acc[r][0]);
            acc[r][0] = fmaf(e4.y, w1.x, acc[r][0]);
            acc[r][0] = fmaf(e4.z, w2.x, acc[r][0]);
            acc[r][0] = fmaf(e4.w, w3.x, acc[r][0]);
            acc[r][1] = fmaf(e4.x, w0.y, acc[r][1]);
            acc[r][1] = fmaf(e4.y, w1.y, acc[r][1]);
            acc[r][1] = fmaf(e4.z, w2.y, acc[r][1]);
            acc[r][1] = fmaf(e4.w, w3.y, acc[r][1]);
            acc[r][2] = fmaf(e4.x, w0.z, acc[r][2]);
            acc[r][2] = fmaf(e4.y, w1.z, acc[r][2]);
            acc[r][2] = fmaf(e4.z, w2.z, acc[r][2]);
            acc[r][2] = fmaf(e4.w, w3.z, acc[r][2]);
            acc[r][3] = fmaf(e4.x, w0.w, acc[r][3]);
            acc[r][3] = fmaf(e4.y, w1.w, acc[r][3]);
            acc[r][3] = fmaf(e4.z, w2.w, acc[r][3]);
            acc[r][3] = fmaf(e4.w, w3.w, acc[r][3]);
        }
    }

    const float4 bj = *(const float4*)&b[j0];
    #pragma unroll
    for (int r = 0; r < 8; ++r) {
        const int row = rb + rg * 8 + r;
        if (row < VOC) {
            float4 o;
            o.x = acc[r][0] + bj.x; o.y = acc[r][1] + bj.y;
            o.z = acc[r][2] + bj.z; o.w = acc[r][3] + bj.w;
            *(float4*)&XW[(size_t)row * G4 + j0] = o;
        }
    }
}

// ---------------- Kernel 2: recurrence, one 1024-thr block per n ----------------
// R12 structure with mod-8 interleaved t' ownership (phase-A load balance).
// Group g owns t' in {g, g+8, g+16, ...}: hreg[i] = h(g+8i). Every group has
// ~t/8 active terms at every t (was: group g idle until t>25g).
// c history in LDS (c_lds[h][209], conflict-free), U in regs (ucol[64]).
// 2 barriers/step; reduce folded into phase B; cell csum in register csr.
__global__ __launch_bounds__(1024) void k2_recur(
    const float* __restrict__ topo,     // (T, N, T)
    const float* __restrict__ mask,     // (T, N)
    const float* __restrict__ U,        // (H, 4H)
    const int*   __restrict__ seq,      // (T, N)
    const float* __restrict__ XW,       // (V, 4H)
    float* __restrict__ hmT)            // (H, N) transposed h_mean
{
    const int n    = blockIdx.x;
    const int tid  = threadIdx.x;
    const int g    = __builtin_amdgcn_readfirstlane(tid >> 7);   // 0..7
    const int h    = tid & 127;
    const int kh   = __builtin_amdgcn_readfirstlane(tid >> 9);   // 0..1
    const int j    = tid & 511;
    const int lane = tid & 63;

    __shared__ float c_lds[HID][209];                 // 104.5 KB, c_lds[h][t']
    __shared__ __align__(16) float topoS[2][8][32];   // topoS[g][i] = row[g+8i]
    __shared__ float part_h[8][HID];
    __shared__ float part_c[8][HID];
    __shared__ float pB[2][G4];
    __shared__ float xgl[2][G4];
    __shared__ int   seq_l[TT];
    __shared__ float mask_l[TT];

    float ucol[64];
    #pragma unroll
    for (int kk = 0; kk < 64; ++kk) ucol[kk] = U[(size_t)(kh * 64 + kk) * G4 + j];

    float hreg[25];                     // hreg[i] = h(g + 8*i)
    #pragma unroll
    for (int k = 0; k < 25; ++k) hreg[k] = 0.f;
    for (int i = tid; i < HID * 209; i += 1024) (&c_lds[0][0])[i] = 0.f;

    // one-time preload: per-n sequence + mask rows (kills per-step s_load chain)
    if (tid < TT) {
        seq_l[tid]  = seq[tid * NBATCH + n];
        mask_l[tid] = mask[tid * NBATCH + n];
    }
    // prologue stage for t=0 (addresses straight from global, uniform)
    if (tid < G4) {
        xgl[0][tid] = XW[(size_t)seq[n] * G4 + tid];
    } else if (tid < 768) {
        const int tt = tid - 512;
        const int gg = tt >> 5, ii = tt & 31;
        topoS[0][gg][ii] = (ii < 25)
            ? topo[(size_t)n * TT + gg + 8 * ii] : 0.f;   // t=0 row, mod-8 layout
    }

    float hmacc = 0.f, len = 0.f;
    __syncthreads();   // once, before loop: full drain is fine

    for (int t = 0; t < TT; ++t) {
        const int cur = t & 1, nxt = cur ^ 1;
        const int gstar = t & 7;        // mod-8 owner
        const int kt = t >> 3;          // slot within owner group

        // ---- issue prefetch for step t+1 (registers; committed before bar C) ----
        const int tn = (t + 1 < TT) ? t + 1 : t;
        float pf = 0.f;
        if (tid < G4) {
            pf = XW[(size_t)seq_l[tn] * G4 + tid];
        } else if (tid < 768) {
            const int tt = tid - 512;
            const int gg = tt >> 5, ii = tt & 31;
            pf = (ii < 25)
                ? topo[((size_t)tn * NBATCH + n) * TT + gg + 8 * ii] : 0.f;
        }
        const float m = mask_l[t];

        // ---- phase A: balanced mod-8 chunks; topo via lane-distribute +
        //      readlane; h from regs, c from LDS (conflict-free b32) ----
        const float tval = topoS[cur][g][lane & 31];   // lane i<25 holds topo[g+8i]
        float ah0 = 0.f, ah1 = 0.f, ac0 = 0.f, ac1 = 0.f;
        const float* crow = &c_lds[h][0];
        #pragma unroll
        for (int kk = 0; kk < 6; ++kk) {
            if (g + 32 * kk < t) {      // perf guard only; data is 0 beyond t
                const float t0 = RL(tval, 4 * kk + 0);
                const float t1 = RL(tval, 4 * kk + 1);
                const float t2 = RL(tval, 4 * kk + 2);
                const float t3 = RL(tval, 4 * kk + 3);
                ah0 = fmaf(t0, hreg[4*kk+0], ah0);
                ac0 = fmaf(t0, crow[g + 32*kk +  0], ac0);
                ah1 = fmaf(t1, hreg[4*kk+1], ah1);
                ac1 = fmaf(t1, crow[g + 32*kk +  8], ac1);
                ah0 = fmaf(t2, hreg[4*kk+2], ah0);
                ac0 = fmaf(t2, crow[g + 32*kk + 16], ac0);
                ah1 = fmaf(t3, hreg[4*kk+3], ah1);
                ac1 = fmaf(t3, crow[g + 32*kk + 24], ac1);
            }
        }
        if (g + 192 < t) {
            const float tpl = RL(tval, 24);
            ah0 = fmaf(tpl, hreg[24], ah0);
            ac0 = fmaf(tpl, crow[g + 192], ac0);
        }
        part_h[g][h] = ah0 + ah1;
        part_c[g][h] = ac0 + ac1;
        BAR_LGKM();                                             // (A)

        // ---- phase B (reduce folded in): hval = sum_gg part_h[gg][col],
        //      then pB[kh][j] = hsum-half . U-half column via readlane ----
        {
            const int col = kh * 64 + lane;
            const float s0 = part_h[0][col] + part_h[1][col];
            const float s1 = part_h[2][col] + part_h[3][col];
            const float s2 = part_h[4][col] + part_h[5][col];
            const float s3 = part_h[6][col] + part_h[7][col];
            const float hval = (s0 + s1) + (s2 + s3);  // lane k holds hsum[kh*64+k]
            float a0 = 0.f, a1 = 0.f, a2 = 0.f, a3 = 0.f;
            #pragma unroll
            for (int q = 0; q < 16; ++q) {
                a0 = fmaf(RL(hval, 4*q+0), ucol[4*q+0], a0);
                a1 = fmaf(RL(hval, 4*q+1), ucol[4*q+1], a1);
                a2 = fmaf(RL(hval, 4*q+2), ucol[4*q+2], a2);
                a3 = fmaf(RL(hval, 4*q+3), ucol[4*q+3], a3);
            }
            pB[kh][j] = (a0 + a1) + (a2 + a3);
        }
        // cell's csum as a register (part_c stable between bars A and C)
        float csr = 0.f;
        if (g == gstar) {
            const float c0 = part_c[0][h] + part_c[1][h];
            const float c1 = part_c[2][h] + part_c[3][h];
            const float c2 = part_c[4][h] + part_c[5][h];
            const float c3 = part_c[6][h] + part_c[7][h];
            csr = (c0 + c1) + (c2 + c3);
        }
        // commit prefetch to the nxt buffers (vmcnt wait lands here)
        if (tid < G4) {
            xgl[nxt][tid] = pf;
        } else if (tid < 768) {
            const int tt = tid - 512;
            topoS[nxt][tt >> 5][tt & 31] = pf;
        }
        BAR_LGKM();                                             // (C)

        // ---- cell: owning group g* = t&7 (wave-uniform branch) ----
        if (g == gstar) {
            const float iv = pB[0][h]       + pB[1][h]       + xgl[cur][h];
            const float fv = pB[0][128+h]   + pB[1][128+h]   + xgl[cur][128+h];
            const float ov = pB[0][256+h]   + pB[1][256+h]   + xgl[cur][256+h];
            const float gv = pB[0][384+h]   + pB[1][384+h]   + xgl[cur][384+h];
            const float si = 1.f / (1.f + expf(-iv));
            const float sf = 1.f / (1.f + expf(-fv));
            const float so = 1.f / (1.f + expf(-ov));
            const float tg = tanhf(gv);
            const float cn = m * (sf * csr + si * tg);
            const float hn = m * (so * tanhf(cn));
            #pragma unroll
            for (int k = 0; k < 25; ++k) if (k == kt) hreg[k] = hn;
            c_lds[h][t] = cn;   // read back only by this same thread (owner g*)
            hmacc = fmaf(m, hn, hmacc);
        }
        len += m;
        // hazards: part_h/part_c written before bar A, read between bars A and C,
        // rewritten next step after bar C. pB written before bar C, read after.
        // xgl[cur]/topoS[cur] read this step; rewritten next step after bar A.
    }

    part_h[g][h] = hmacc;     // unique slot per thread
    __syncthreads();
    if (tid < HID) {
        float s = 0.f;
        #pragma unroll
        for (int gg = 0; gg < 8; ++gg) s += part_h[gg][tid];
        hmT[(size_t)tid * NBATCH + n] = s / len;   // transposed for k3
    }
}

// ---------------- Kernel 3: out = h_mean @ W_out + b_out  (k-outer matvec) ----------------
// 512 thr: thread owns 4 consecutive v (float4 Wout loads, 16B/lane) x 16 rows.
// grid (25, 16). s_loads for hmT row-slice halved vs 32-row version.
__global__ __launch_bounds__(512) void k3_out(
    const float* __restrict__ hmT,     // (H, N)
    const float* __restrict__ Wout,    // (H, V)
    const float* __restrict__ bout,    // (V)
    float* __restrict__ out)           // (N, V)
{
    const int tid = threadIdx.x;
    const int v0 = blockIdx.x * 2048 + tid * 4;
    const int r0 = blockIdx.y * 16;
    const int vc = v0 < VOC ? v0 : VOC - 4;   // VOC % 4 == 0: aligned clamp

    float acc[16][4];
    #pragma unroll
    for (int r = 0; r < 16; ++r) {
        acc[r][0] = 0.f; acc[r][1] = 0.f; acc[r][2] = 0.f; acc[r][3] = 0.f;
    }

    #pragma unroll 2
    for (int k = 0; k < HID; ++k) {
        const float4 wv = *(const float4*)&Wout[(size_t)k * VOC + vc];  // coalesced
        const float* hr = hmT + k * NBATCH + r0;       // uniform -> s_load
        #pragma unroll
        for (int r = 0; r < 16; ++r) {
            const float hv = hr[r];
            acc[r][0] = fmaf(hv, wv.x, acc[r][0]);
            acc[r][1] = fmaf(hv, wv.y, acc[r][1]);
            acc[r][2] = fmaf(hv, wv.z, acc[r][2]);
            acc[r][3] = fmaf(hv, wv.w, acc[r][3]);
        }
    }
    if (v0 < VOC) {
        const float4 bv = *(const float4*)&bout[v0];
        #pragma unroll
        for (int r = 0; r < 16; ++r) {
            float4 o;
            o.x = acc[r][0] + bv.x; o.y = acc[r][1] + bv.y;
            o.z = acc[r][2] + bv.z; o.w = acc[r][3] + bv.w;
            *(float4*)&out[(size_t)(r0 + r) * VOC + v0] = o;
        }
    }
}

extern "C" void kernel_launch(void* const* d_in, const int* in_sizes, int n_in,
                              void* d_out, int out_size, void* d_ws, size_t ws_size,
                              hipStream_t stream) {
    const int*   seq  = (const int*)d_in[0];     // (T,N) int32
    const float* msk  = (const float*)d_in[1];   // (T,N)
    const float* topo = (const float*)d_in[2];   // (T,N,T)
    const float* W    = (const float*)d_in[3];   // (H,4H)
    const float* U    = (const float*)d_in[4];   // (H,4H)
    const float* b    = (const float*)d_in[5];   // (4H)
    const float* ET   = (const float*)d_in[6];   // (V,H)
    const float* Wout = (const float*)d_in[7];   // (H,V)
    const float* bout = (const float*)d_in[8];   // (V)
    float* out = (float*)d_out;

    float* XW  = (float*)d_ws;                                   // 102.4 MB
    float* hmT = (float*)((char*)d_ws + (size_t)VOC * G4 * sizeof(float)); // +128 KB

    kxw<<<(VOC + 31) / 32, 512, 0, stream>>>(ET, W, b, XW);
    k2_recur<<<NBATCH, 1024, 0, stream>>>(topo, msk, U, seq, XW, hmT);
    k3_out<<<dim3(25, 16), 512, 0, stream>>>(hmT, Wout, bout, out);
}